// Round 8
// baseline (202.258 us; speedup 1.0000x reference)
//
#include <hip/hip_runtime.h>
#include <math.h>

// Problem: scores = q[2048x768] @ p[16384x768]^T (fp32 in), per-query
// rank-of-target + log-softmax CE + Gaussian rank weight -> mean (scalar).
// R8: BARRIER-FREE direct-VMEM fp8 GEMM. No LDS, no __syncthreads in the
// K-loop: each wave loads its own A/B fragments from global (L1/L2-resident)
// as 16B/lane dwordx4 (16 rows x 64B = 16 full sectors = coalesced-equal).
// k-permutation trick: lane holds k=lq*16..+16; split into lo8/hi8 for two
// 16x16x32 fp8 MFMAs — any k-permutation consistent across A and B is a
// valid contraction order. R5/R7 lesson: every 2-barrier K-loop variant
// plateaus at 25-35% MFMA rate (vmcnt(0) drain stalls all waves); removing
// the barrier removes the straggler coupling.

#define BQ 2048
#define DD 768
#define NPASS 8
#define PP 16384
#define BM 256
#define BN 128
#define KITERS 12          // 768/64
#define NBLK 128           // PP/BN
#define MBLK 8             // BQ/BM
#define NCHUNKS 256        // NBLK * 2 wn-groups

#define ALPHA_C 2.6f
#define INV_2SIG2 (1.0f/6.48f)   // 1/(2*1.8^2)

typedef __attribute__((ext_vector_type(4))) float floatx4;  // MFMA C/D
typedef __attribute__((ext_vector_type(2))) long long2v;    // 16B = 2 MFMA operands

// ---------------------------------------------------------------------------
// Kernel 1 (fused): cast q,p -> fp8 e4m3  +  s_t exact-fp32 dots  +  out=0.
// ---------------------------------------------------------------------------
#define NQ8   196608     // 2048*768/8
#define NTOT8 1769472    // (2048+16384)*768/8
#define NCB   6912       // NTOT8/256
__global__ __launch_bounds__(256) void prep_kernel(const float* __restrict__ qf,
                                                   const float* __restrict__ pf,
                                                   uint2* __restrict__ qb,
                                                   uint2* __restrict__ pb,
                                                   float* __restrict__ st,
                                                   float* __restrict__ out) {
  const int b = blockIdx.x;
  if (b == 0 && threadIdx.x == 0) *out = 0.f;
  if (b < NCB) {
    const int i = b * 256 + threadIdx.x;        // float8 index
    const float4* src; uint2* dst;
    if (i < NQ8) { src = (const float4*)qf + 2 * (size_t)i; dst = qb + i; }
    else { const size_t j = (size_t)i - NQ8; src = (const float4*)pf + 2 * j; dst = pb + j; }
    const float4 a = src[0], c = src[1];
    unsigned lo = __builtin_amdgcn_cvt_pk_fp8_f32(a.x, a.y, 0, 0);
    lo = __builtin_amdgcn_cvt_pk_fp8_f32(a.z, a.w, lo, 1);
    unsigned hi = __builtin_amdgcn_cvt_pk_fp8_f32(c.x, c.y, 0, 0);
    hi = __builtin_amdgcn_cvt_pk_fp8_f32(c.z, c.w, hi, 1);
    uint2 w; w.x = lo; w.y = hi;
    *dst = w;
  } else {
    const int wv = threadIdx.x >> 6, lane = threadIdx.x & 63;
    const int qi = (b - NCB) * 4 + wv;
    const float4* q4 = (const float4*)(qf + (size_t)qi * DD);
    const float4* p4 = (const float4*)(pf + (size_t)qi * NPASS * DD);
    float acc = 0.f;
#pragma unroll
    for (int u = 0; u < 3; ++u) {
      float4 a = q4[lane + 64 * u];
      float4 c = p4[lane + 64 * u];
      acc = fmaf(a.x, c.x, acc);
      acc = fmaf(a.y, c.y, acc);
      acc = fmaf(a.z, c.z, acc);
      acc = fmaf(a.w, c.w, acc);
    }
#pragma unroll
    for (int off = 32; off >= 1; off >>= 1) acc += __shfl_xor(acc, off);
    if (lane == 0) st[qi] = acc;
  }
}

// ---------------------------------------------------------------------------
// Kernel 2: barrier-free fp8 MFMA GEMM 256x128, no LDS.
// 8 waves as 4 wm x 2 wn; each wave owns a 64x64 output tile (4x4 frags of
// 16x16). Per kt (64 k): 4 A-loads + 4 B-loads (dwordx4/lane), then
// 4x4x2 = 32 MFMAs. Fragment addressing: lane(lm=lane&15, lq=lane>>4)
// reads row (tile + frag*16 + lm), bytes kt*64 + lq*16 .. +16.
// C/D: col=lane&15, row=(lane>>4)*4+reg (validated R2-R7).
// Grid: mb=bid&7 (one m-slice per XCD, 196 KB L2-resident), nb=bid>>3.
// ---------------------------------------------------------------------------
__global__ __launch_bounds__(512, 4) void gemm_kernel(const unsigned char* __restrict__ qb,
                                                      const unsigned char* __restrict__ pb,
                                                      const float* __restrict__ st,
                                                      float* __restrict__ pm,
                                                      float* __restrict__ pl,
                                                      float* __restrict__ pc) {
  const int t = threadIdx.x;
  const int lane = t & 63;
  const int wv = t >> 6;            // 0..7
  const int wm = wv >> 1, wn = wv & 1;
  const int bid = blockIdx.x;
  const int mb = bid & 7;           // XCD round-robin: one m-slice per XCD
  const int nb = bid >> 3;
  const int qbase = mb * BM;
  const int n0 = nb * BN;
  const int lm = lane & 15;
  const int lq = lane >> 4;

  floatx4 acc[4][4];
#pragma unroll
  for (int i = 0; i < 4; ++i)
#pragma unroll
    for (int j = 0; j < 4; ++j) acc[i][j] = (floatx4){0.f, 0.f, 0.f, 0.f};

  // per-lane fragment base pointers (row*DD + lq*16), frag i at +i*16*DD
  const unsigned char* ap = qb + (size_t)(qbase + wm * 64 + lm) * DD + lq * 16;
  const unsigned char* bp = pb + (size_t)(n0 + wn * 64 + lm) * DD + lq * 16;

  for (int kt = 0; kt < KITERS; ++kt) {
    const int ko = kt * 64;
    long2v a[4], b[4];
#pragma unroll
    for (int i = 0; i < 4; ++i)
      a[i] = *(const long2v*)(ap + i * (16 * DD) + ko);
#pragma unroll
    for (int j = 0; j < 4; ++j)
      b[j] = *(const long2v*)(bp + j * (16 * DD) + ko);
#pragma unroll
    for (int i = 0; i < 4; ++i)
#pragma unroll
      for (int j = 0; j < 4; ++j) {
        acc[i][j] = __builtin_amdgcn_mfma_f32_16x16x32_fp8_fp8(a[i].x, b[j].x, acc[i][j], 0, 0, 0);
        acc[i][j] = __builtin_amdgcn_mfma_f32_16x16x32_fp8_fp8(a[i].y, b[j].y, acc[i][j], 0, 0, 0);
      }
  }

  // ---- fused epilogue: per-row (query) max / sumexp / count over 64 cols ----
#pragma unroll
  for (int i = 0; i < 4; ++i) {
#pragma unroll
    for (int r = 0; r < 4; ++r) {
      const int rl = wm * 64 + i * 16 + lq * 4 + r;   // local query row
      const int qg = qbase + rl;
      float mx = fmaxf(fmaxf(acc[i][0][r], acc[i][1][r]),
                       fmaxf(acc[i][2][r], acc[i][3][r]));
#pragma unroll
      for (int off = 1; off <= 8; off <<= 1) mx = fmaxf(mx, __shfl_xor(mx, off));
      const float stv = st[qg];
      const int tcol = qg * NPASS;
      float sum = 0.f, c = 0.f;
#pragma unroll
      for (int j = 0; j < 4; ++j) {
        const float s = acc[i][j][r];
        sum += __expf(s - mx);
        const int cg = n0 + wn * 64 + j * 16 + lm;
        if (s > stv && cg != tcol) c += 1.f;
      }
#pragma unroll
      for (int off = 1; off <= 8; off <<= 1) {
        sum += __shfl_xor(sum, off);
        c += __shfl_xor(c, off);
      }
      if (lm == 0) {
        const int chunk = nb * 2 + wn;
        const size_t idx = (size_t)qg * NCHUNKS + chunk;
        pm[idx] = mx; pl[idx] = sum; pc[idx] = c;
      }
    }
  }
}

// ---------------------------------------------------------------------------
// Kernel 3: merge 256 chunks/query, weighted CE, mean -> atomicAdd. 1 wave/query.
// ---------------------------------------------------------------------------
__global__ __launch_bounds__(256) void finalize_kernel(const float* __restrict__ st,
                                                       const float* __restrict__ pm,
                                                       const float* __restrict__ pl,
                                                       const float* __restrict__ pc,
                                                       float* __restrict__ out) {
  const int wv = threadIdx.x >> 6, lane = threadIdx.x & 63;
  const int qi = blockIdx.x * 4 + wv;
  float4 m4 = ((const float4*)(pm + (size_t)qi * NCHUNKS))[lane];
  float mx = fmaxf(fmaxf(m4.x, m4.y), fmaxf(m4.z, m4.w));
#pragma unroll
  for (int off = 32; off >= 1; off >>= 1) mx = fmaxf(mx, __shfl_xor(mx, off));
  float4 l4 = ((const float4*)(pl + (size_t)qi * NCHUNKS))[lane];
  float4 c4 = ((const float4*)(pc + (size_t)qi * NCHUNKS))[lane];
  float l = l4.x * __expf(m4.x - mx) + l4.y * __expf(m4.y - mx) +
            l4.z * __expf(m4.z - mx) + l4.w * __expf(m4.w - mx);
  float c = c4.x + c4.y + c4.z + c4.w;
#pragma unroll
  for (int off = 32; off >= 1; off >>= 1) {
    l += __shfl_xor(l, off);
    c += __shfl_xor(c, off);
  }
  float loss = 0.f;
  if (lane == 0) {
    const float raw = logf(l) + mx - st[qi];   // -log_softmax[target]
    const float dr = c - 1.0f;                 // rank - OPTIMAL_RANK
    const float w = 1.0f + ALPHA_C * __expf(-(dr * dr) * INV_2SIG2);
    loss = raw * w * (1.0f / (float)BQ);
  }
  __shared__ float red[4];
  if (lane == 0) red[wv] = loss;
  __syncthreads();
  if (threadIdx.x == 0) atomicAdd(out, red[0] + red[1] + red[2] + red[3]);
}

// ---------------------------------------------------------------------------
extern "C" void kernel_launch(void* const* d_in, const int* in_sizes, int n_in,
                              void* d_out, int out_size, void* d_ws, size_t ws_size,
                              hipStream_t stream) {
  const float* q = (const float*)d_in[0];
  const float* p = (const float*)d_in[1];
  char* ws = (char*)d_ws;
  unsigned char* qb = (unsigned char*)ws;                  // 1,572,864 B
  unsigned char* pb = (unsigned char*)(ws + 1572864);      // 12,582,912 B
  float* st = (float*)(ws + 14155776);                     // 8 KB
  float* pm = (float*)(ws + 14163968);                     // 2 MB
  float* pl = (float*)(ws + 16261120);                     // 2 MB
  float* pc = (float*)(ws + 18358272);                     // 2 MB (end ~20.5 MB)
  float* out = (float*)d_out;

  prep_kernel<<<NCB + BQ / 4, 256, 0, stream>>>(q, p, (uint2*)qb, (uint2*)pb, st, out);
  gemm_kernel<<<NBLK * MBLK, 512, 0, stream>>>(qb, pb, st, pm, pl, pc);
  finalize_kernel<<<BQ / 4, 256, 0, stream>>>(st, pm, pl, pc, out);
}